// Round 3
// baseline (1571.005 us; speedup 1.0000x reference)
//
#include <hip/hip_runtime.h>
#include <hip/hip_bf16.h>
#include <cstddef>

#define N_NODES 100000
#define N_EDGES 600000
#define DD 128
#define LL 3
#define CC 40
#define BN_EPS 1e-5f

// dtype-adaptive load/store: f32!=0 -> buffer holds float32, else bfloat16.
__device__ __forceinline__ float ldf(const void* p, long i, int f32) {
    return f32 ? ((const float*)p)[i] : __bfloat162float(((const __hip_bfloat16*)p)[i]);
}
__device__ __forceinline__ void stf(void* p, long i, float v, int f32) {
    if (f32) ((float*)p)[i] = v;
    else     ((__hip_bfloat16*)p)[i] = __float2bfloat16(v);
}

// ---------------- dtype detection (fp32 data read as bf16 -> garbage values) ----------------
__global__ __launch_bounds__(256) void k_detect(const void* __restrict__ x, int* __restrict__ dflag) {
    __shared__ int s[256];
    int t = threadIdx.x;
    const __hip_bfloat16* xb = (const __hip_bfloat16*)x;
    int bad = 0;
    for (int i = t; i < 4096; i += 256) {
        float v = __bfloat162float(xb[i]);
        float a = fabsf(v);
        if (!(a < 1e6f)) bad++;
        else if (v != 0.f && a < 1e-30f) bad++;
    }
    s[t] = bad; __syncthreads();
    for (int off = 128; off > 0; off >>= 1) {
        if (t < off) s[t] += s[t + off];
        __syncthreads();
    }
    if (t == 0) *dflag = (s[0] > 64) ? 1 : 0;
}

// ---------------- graph preprocessing ----------------

__global__ __launch_bounds__(256) void k_init(int* cnt, int* fpos, int* rowptr, float* stats) {
    int i = blockIdx.x * 256 + threadIdx.x;
    if (i < N_NODES) { cnt[i] = 0; fpos[i] = 0; }
    if (i < 6 * DD) stats[i] = 0.f;
    if (i == 0) rowptr[N_NODES] = N_EDGES;
}

__global__ __launch_bounds__(256) void k_count(const int* __restrict__ ei, int* __restrict__ cnt) {
    int e = blockIdx.x * 256 + threadIdx.x;
    if (e < N_EDGES) atomicAdd(&cnt[ei[N_EDGES + e]], 1);  // dst row
}

__global__ __launch_bounds__(256) void k_scan1(const int* __restrict__ cnt, int* __restrict__ rowptr,
                                               int* __restrict__ bsum, float* __restrict__ dinv) {
    __shared__ int s[256];
    int t = threadIdx.x;
    int i = blockIdx.x * 256 + t;
    int v = (i < N_NODES) ? cnt[i] : 0;
    if (i < N_NODES) dinv[i] = 1.f / sqrtf((float)(1 + v));  // deg >= 1 (self-loop)
    s[t] = v; __syncthreads();
    for (int off = 1; off < 256; off <<= 1) {
        int x = (t >= off) ? s[t - off] : 0;
        __syncthreads();
        s[t] += x; __syncthreads();
    }
    if (i < N_NODES) rowptr[i] = s[t] - v;
    if (t == 255) bsum[blockIdx.x] = s[255];
}

__global__ __launch_bounds__(512) void k_scan2(int* bsum, int nb) {
    __shared__ int s[512];
    int t = threadIdx.x;
    int v = (t < nb) ? bsum[t] : 0;
    s[t] = v; __syncthreads();
    for (int off = 1; off < 512; off <<= 1) {
        int x = (t >= off) ? s[t - off] : 0;
        __syncthreads();
        s[t] += x; __syncthreads();
    }
    if (t < nb) bsum[t] = s[t] - v;
}

__global__ __launch_bounds__(256) void k_scan3(int* rowptr, const int* __restrict__ bsum) {
    int i = blockIdx.x * 256 + threadIdx.x;
    if (i < N_NODES) rowptr[i] += bsum[blockIdx.x];
}

__global__ __launch_bounds__(256) void k_fill(const int* __restrict__ ei, int* __restrict__ fpos,
                                              const int* __restrict__ rowptr, int* __restrict__ adj) {
    int e = blockIdx.x * 256 + threadIdx.x;
    if (e < N_EDGES) {
        int d = ei[N_EDGES + e];
        int p = atomicAdd(&fpos[d], 1);
        adj[rowptr[d] + p] = ei[e];
    }
}

// ---- fp32 GEMM: C[N x 128] = act(A)[N x 128] * W[128 x 128] (+bias, relu) ----
// 128x128 block tile, BK=32, 256 threads, 8x8 acc/thread.
// bnp != null: A is fp32, act = PReLU(a*scale[k]+shift[k]) (fused BatchNorm).
// bnp == null: A loaded via dtype flag, no activation.

__global__ __launch_bounds__(256) void k_gemm(const void* __restrict__ A, const void* __restrict__ W,
                                              long woff, const void* __restrict__ bias,
                                              const float* __restrict__ bnp,
                                              float* __restrict__ Cout, int relu,
                                              const int* __restrict__ dflag) {
    __shared__ float At[32][132];   // [k][row], pad 132: float4-aligned rows
    __shared__ float Wt[32][132];   // [k][col]
    int f = *dflag;
    int tid = threadIdx.x;
    int rowbase = blockIdx.x * 128;
    int tx = tid & 15;              // cols tx*8 .. tx*8+7
    int ty = tid >> 4;              // rows ty*8 .. ty*8+7
    float al = bnp ? bnp[256] : 0.f;
    float acc[8][8];
    #pragma unroll
    for (int i = 0; i < 8; ++i)
        #pragma unroll
        for (int j = 0; j < 8; ++j) acc[i][j] = 0.f;

    for (int kt = 0; kt < 128; kt += 32) {
        #pragma unroll
        for (int i = 0; i < 16; ++i) {          // stage A (transposed, BN fused)
            int u = tid + i * 256;
            int r = u >> 5, k = u & 31;
            int gr = rowbase + r;
            float v = 0.f;
            if (gr < N_NODES) {
                if (bnp) {
                    float a = ((const float*)A)[(long)gr * 128 + kt + k];
                    v = fmaf(a, bnp[kt + k], bnp[128 + kt + k]);
                    v = (v > 0.f) ? v : al * v;
                } else {
                    v = ldf(A, (long)gr * 128 + kt + k, f);
                }
            }
            At[k][r] = v;
        }
        #pragma unroll
        for (int i = 0; i < 16; ++i) {          // stage W
            int u = tid + i * 256;
            int k = u >> 7, c = u & 127;
            Wt[k][c] = ldf(W, woff + (long)(kt + k) * 128 + c, f);
        }
        __syncthreads();
        #pragma unroll
        for (int k = 0; k < 32; ++k) {
            float4 a0 = *(const float4*)&At[k][ty * 8];
            float4 a1 = *(const float4*)&At[k][ty * 8 + 4];
            float4 w0 = *(const float4*)&Wt[k][tx * 8];
            float4 w1 = *(const float4*)&Wt[k][tx * 8 + 4];
            float av[8] = {a0.x, a0.y, a0.z, a0.w, a1.x, a1.y, a1.z, a1.w};
            float wv[8] = {w0.x, w0.y, w0.z, w0.w, w1.x, w1.y, w1.z, w1.w};
            #pragma unroll
            for (int i = 0; i < 8; ++i)
                #pragma unroll
                for (int j = 0; j < 8; ++j) acc[i][j] += av[i] * wv[j];
        }
        __syncthreads();
    }
    #pragma unroll
    for (int i = 0; i < 8; ++i) {
        int r = rowbase + ty * 8 + i;
        if (r < N_NODES) {
            float o[8];
            #pragma unroll
            for (int j = 0; j < 8; ++j) {
                float v = acc[i][j];
                if (bias) v += ldf(bias, tx * 8 + j, f);
                if (relu) v = fmaxf(v, 0.f);
                o[j] = v;
            }
            *(float4*)&Cout[(long)r * 128 + tx * 8]     = make_float4(o[0], o[1], o[2], o[3]);
            *(float4*)&Cout[(long)r * 128 + tx * 8 + 4] = make_float4(o[4], o[5], o[6], o[7]);
        }
    }
}

// ---- CSR aggregation: out_i = dinv_i*(dinv_i*XW_i + sum_j dinv_j*XW_j) + b ----

__global__ __launch_bounds__(256) void k_agg(const float* __restrict__ XW, const int* __restrict__ rowptr,
                                             const int* __restrict__ adj, const float* __restrict__ dinv,
                                             const void* __restrict__ bias, long boff,
                                             float* __restrict__ outp, const int* __restrict__ dflag) {
    int f = *dflag;
    int wave = threadIdx.x >> 6;
    int lane = threadIdx.x & 63;
    int i = blockIdx.x * 4 + wave;
    if (i >= N_NODES) return;
    const float2* XW2 = (const float2*)XW;
    float di = dinv[i];
    int e0 = rowptr[i], e1 = rowptr[i + 1];
    float2 self = XW2[(size_t)i * 64 + lane];
    float acc0 = di * self.x, acc1 = di * self.y;
    for (int e = e0; e < e1; ++e) {
        int j = adj[e];
        float dj = dinv[j];
        float2 v = XW2[(size_t)j * 64 + lane];
        acc0 += dj * v.x;
        acc1 += dj * v.y;
    }
    float2 r;
    r.x = di * acc0 + ldf(bias, boff + 2 * lane, f);
    r.y = di * acc1 + ldf(bias, boff + 2 * lane + 1, f);
    ((float2*)outp)[(size_t)i * 64 + lane] = r;
}

// ---------------- BatchNorm stats + param prep ----------------

__global__ __launch_bounds__(256) void k_bn_reduce(const float* __restrict__ H, float* __restrict__ sums,
                                                   float* __restrict__ sumsq) {
    int c = threadIdx.x & 127;
    int half = threadIdx.x >> 7;
    float s = 0.f, q = 0.f;
    for (int r = blockIdx.x * 2 + half; r < N_NODES; r += gridDim.x * 2) {
        float v = H[(long)r * 128 + c];
        s += v; q += v * v;
    }
    __shared__ float ls[256], lq[256];
    ls[threadIdx.x] = s; lq[threadIdx.x] = q;
    __syncthreads();
    if (threadIdx.x < 128) {
        atomicAdd(&sums[c], ls[threadIdx.x] + ls[threadIdx.x + 128]);
        atomicAdd(&sumsq[c], lq[threadIdx.x] + lq[threadIdx.x + 128]);
    }
}

// scale[c]=gamma*rsqrt(var+eps); shift[c]=beta-mean*scale; [256]=prelu alpha
__global__ __launch_bounds__(128) void k_bnprep(const float* __restrict__ stats,
                                                const void* __restrict__ g, const void* __restrict__ b,
                                                const void* __restrict__ a, int l,
                                                float* __restrict__ bnp, const int* __restrict__ dflag) {
    int f = *dflag;
    int c = threadIdx.x;
    float mean = stats[c] / (float)N_NODES;
    float var = stats[128 + c] / (float)N_NODES - mean * mean;
    float inv = 1.f / sqrtf(var + BN_EPS);
    float s = ldf(g, (long)l * DD + c, f) * inv;
    bnp[c] = s;
    bnp[128 + c] = ldf(b, (long)l * DD + c, f) - mean * s;
    if (c == 0) bnp[256] = ldf(a, l, f);
}

// emb output: BN+PReLU applied to layer-3 pre-activation, stored in out dtype
__global__ __launch_bounds__(256) void k_emb(const float* __restrict__ H, const float* __restrict__ bnp,
                                             void* __restrict__ out, const int* __restrict__ dflag) {
    int f = *dflag;
    long idx = (long)blockIdx.x * 256 + threadIdx.x;   // grid covers exactly N*DD
    int c = (int)(idx & 127);
    float al = bnp[256];
    float y = fmaf(H[idx], bnp[c], bnp[128 + c]);
    y = (y > 0.f) ? y : al * y;
    stf(out, idx, y, f);
}

// ---- head: logits = hidden @ Wh2 + bh2 ; argmax (first-max tie-break) ----

__global__ __launch_bounds__(256) void k_head(const float* __restrict__ Hd, const void* __restrict__ W2,
                                              const void* __restrict__ b2,
                                              void* __restrict__ out_base,
                                              const int* __restrict__ dflag) {
    __shared__ float Wl[128][40];
    __shared__ float bl[40];
    __shared__ float rv[32][8];
    __shared__ int ri[32][8];
    int f = *dflag;
    int tid = threadIdx.x;
    for (int u = tid; u < 128 * 40; u += 256) Wl[u / 40][u % 40] = ldf(W2, u, f);
    if (tid < 40) bl[tid] = ldf(b2, tid, f);
    __syncthreads();
    int rl = tid >> 3, g = tid & 7;
    long r = (long)blockIdx.x * 32 + rl;            // 3125*32 == N exactly
    float acc[5];
    #pragma unroll
    for (int j = 0; j < 5; ++j) acc[j] = bl[g * 5 + j];
    for (int k = 0; k < 128; ++k) {
        float h = Hd[r * 128 + k];
        #pragma unroll
        for (int j = 0; j < 5; ++j) acc[j] += h * Wl[k][g * 5 + j];
    }
    float best = acc[0]; int bi = 0;
    #pragma unroll
    for (int j = 1; j < 5; ++j)
        if (acc[j] > best) { best = acc[j]; bi = j; }   // strictly > keeps first max
    const long LOG_OFF = (long)N_NODES * DD;
    const long ARG_OFF = (long)N_NODES * (DD + CC);
    #pragma unroll
    for (int j = 0; j < 5; ++j) stf(out_base, LOG_OFF + r * 40 + g * 5 + j, acc[j], f);
    rv[rl][g] = best; ri[rl][g] = g * 5 + bi;
    __syncthreads();
    if (tid < 32) {
        long row = (long)blockIdx.x * 32 + tid;
        float bb = rv[tid][0]; int bbi = ri[tid][0];
        #pragma unroll
        for (int g2 = 1; g2 < 8; ++g2)
            if (rv[tid][g2] > bb) { bb = rv[tid][g2]; bbi = ri[tid][g2]; }
        stf(out_base, ARG_OFF + row, (float)bbi, f);
    }
}

// ---------------- launch ----------------

extern "C" void kernel_launch(void* const* d_in, const int* in_sizes, int n_in,
                              void* d_out, int out_size, void* d_ws, size_t ws_size,
                              hipStream_t stream) {
    const void* x   = d_in[0];
    const int* ei   = (const int*)d_in[1];
    const void* Ws  = d_in[2];
    const void* bs  = d_in[3];
    const void* gam = d_in[4];
    const void* bet = d_in[5];
    const void* pa  = d_in[6];
    const void* Wh1 = d_in[7];
    const void* bh1 = d_in[8];
    const void* Wh2 = d_in[9];
    const void* bh2 = d_in[10];

    char* w = (char*)d_ws;
    int* cnt     = (int*)w;    w += sizeof(int) * N_NODES;
    int* fpos    = (int*)w;    w += sizeof(int) * N_NODES;
    int* rowptr  = (int*)w;    w += sizeof(int) * (N_NODES + 4);
    int* adj     = (int*)w;    w += sizeof(int) * N_EDGES;
    int* bsum    = (int*)w;    w += sizeof(int) * 512;
    int* dflag   = (int*)w;    w += sizeof(int) * 4;
    float* dinv  = (float*)w;  w += sizeof(float) * N_NODES;
    float* stats = (float*)w;  w += sizeof(float) * (6 * DD);
    float* bnp   = (float*)w;  w += sizeof(float) * (3 * 512);
    float* bufA  = (float*)w;  w += sizeof(float) * (size_t)N_NODES * DD;
    float* bufB  = (float*)w;  w += sizeof(float) * (size_t)N_NODES * DD;

    const int scanBlocks = (N_NODES + 255) / 256;       // 391
    const int edgeBlocks = (N_EDGES + 255) / 256;       // 2344
    const int elemBlocks = (N_NODES * DD) / 256;        // 50000 exact
    const int gemmBlocks = (N_NODES + 127) / 128;       // 782

    k_detect<<<1, 256, 0, stream>>>(x, dflag);
    k_init<<<scanBlocks, 256, 0, stream>>>(cnt, fpos, rowptr, stats);
    k_count<<<edgeBlocks, 256, 0, stream>>>(ei, cnt);
    k_scan1<<<scanBlocks, 256, 0, stream>>>(cnt, rowptr, bsum, dinv);
    k_scan2<<<1, 512, 0, stream>>>(bsum, scanBlocks);
    k_scan3<<<scanBlocks, 256, 0, stream>>>(rowptr, bsum);
    k_fill<<<edgeBlocks, 256, 0, stream>>>(ei, fpos, rowptr, adj);

    for (int l = 0; l < LL; ++l) {
        const void* Ain = (l == 0) ? x : (const void*)bufA;
        const float* bn = (l == 0) ? nullptr : (bnp + (l - 1) * 512);
        k_gemm<<<gemmBlocks, 256, 0, stream>>>(Ain, Ws, (long)l * DD * DD, nullptr, bn,
                                               bufB, 0, dflag);
        k_agg<<<(N_NODES + 3) / 4, 256, 0, stream>>>(bufB, rowptr, adj, dinv, bs, (long)l * DD,
                                                     bufA, dflag);
        k_bn_reduce<<<256, 256, 0, stream>>>(bufA, stats + l * 2 * DD, stats + l * 2 * DD + DD);
        k_bnprep<<<1, 128, 0, stream>>>(stats + l * 2 * DD, gam, bet, pa, l, bnp + l * 512, dflag);
    }

    k_emb<<<elemBlocks, 256, 0, stream>>>(bufA, bnp + 2 * 512, d_out, dflag);
    k_gemm<<<gemmBlocks, 256, 0, stream>>>(bufA, Wh1, 0, bh1, bnp + 2 * 512, bufB, 1, dflag);
    k_head<<<(N_NODES / 32), 256, 0, stream>>>(bufB, Wh2, bh2, d_out, dflag);
}

// Round 4
// 1029.193 us; speedup vs baseline: 1.5264x; 1.5264x over previous
//
#include <hip/hip_runtime.h>
#include <hip/hip_bf16.h>
#include <cstddef>

#define N_NODES 100000
#define N_EDGES 600000
#define DD 128
#define LL 3
#define CC 40
#define BN_EPS 1e-5f

// dtype-adaptive load/store: f32!=0 -> buffer holds float32, else bfloat16.
__device__ __forceinline__ float ldf(const void* p, long i, int f32) {
    return f32 ? ((const float*)p)[i] : __bfloat162float(((const __hip_bfloat16*)p)[i]);
}
__device__ __forceinline__ void stf(void* p, long i, float v, int f32) {
    if (f32) ((float*)p)[i] = v;
    else     ((__hip_bfloat16*)p)[i] = __float2bfloat16(v);
}

// ---------------- dtype detection (fp32 data read as bf16 -> garbage values) ----------------
__global__ __launch_bounds__(256) void k_detect(const void* __restrict__ x, int* __restrict__ dflag) {
    __shared__ int s[256];
    int t = threadIdx.x;
    const __hip_bfloat16* xb = (const __hip_bfloat16*)x;
    int bad = 0;
    for (int i = t; i < 4096; i += 256) {
        float v = __bfloat162float(xb[i]);
        float a = fabsf(v);
        if (!(a < 1e6f)) bad++;
        else if (v != 0.f && a < 1e-30f) bad++;
    }
    s[t] = bad; __syncthreads();
    for (int off = 128; off > 0; off >>= 1) {
        if (t < off) s[t] += s[t + off];
        __syncthreads();
    }
    if (t == 0) *dflag = (s[0] > 64) ? 1 : 0;
}

// ---------------- graph preprocessing ----------------

__global__ __launch_bounds__(256) void k_init(int* cnt, int* fpos, int* rowptr, float* stats) {
    int i = blockIdx.x * 256 + threadIdx.x;
    if (i < N_NODES) { cnt[i] = 0; fpos[i] = 0; }
    if (i < 6 * DD) stats[i] = 0.f;
    if (i == 0) rowptr[N_NODES] = N_EDGES;
}

__global__ __launch_bounds__(256) void k_count(const int* __restrict__ ei, int* __restrict__ cnt) {
    int e = blockIdx.x * 256 + threadIdx.x;
    if (e < N_EDGES) atomicAdd(&cnt[ei[N_EDGES + e]], 1);  // dst row
}

__global__ __launch_bounds__(256) void k_scan1(const int* __restrict__ cnt, int* __restrict__ rowptr,
                                               int* __restrict__ bsum, float* __restrict__ dinv) {
    __shared__ int s[256];
    int t = threadIdx.x;
    int i = blockIdx.x * 256 + t;
    int v = (i < N_NODES) ? cnt[i] : 0;
    if (i < N_NODES) dinv[i] = 1.f / sqrtf((float)(1 + v));  // deg >= 1 (self-loop)
    s[t] = v; __syncthreads();
    for (int off = 1; off < 256; off <<= 1) {
        int x = (t >= off) ? s[t - off] : 0;
        __syncthreads();
        s[t] += x; __syncthreads();
    }
    if (i < N_NODES) rowptr[i] = s[t] - v;
    if (t == 255) bsum[blockIdx.x] = s[255];
}

__global__ __launch_bounds__(512) void k_scan2(int* bsum, int nb) {
    __shared__ int s[512];
    int t = threadIdx.x;
    int v = (t < nb) ? bsum[t] : 0;
    s[t] = v; __syncthreads();
    for (int off = 1; off < 512; off <<= 1) {
        int x = (t >= off) ? s[t - off] : 0;
        __syncthreads();
        s[t] += x; __syncthreads();
    }
    if (t < nb) bsum[t] = s[t] - v;
}

__global__ __launch_bounds__(256) void k_scan3(int* rowptr, const int* __restrict__ bsum) {
    int i = blockIdx.x * 256 + threadIdx.x;
    if (i < N_NODES) rowptr[i] += bsum[blockIdx.x];
}

__global__ __launch_bounds__(256) void k_fill(const int* __restrict__ ei, int* __restrict__ fpos,
                                              const int* __restrict__ rowptr, int* __restrict__ adj) {
    int e = blockIdx.x * 256 + threadIdx.x;
    if (e < N_EDGES) {
        int d = ei[N_EDGES + e];
        int p = atomicAdd(&fpos[d], 1);
        adj[rowptr[d] + p] = ei[e];
    }
}

// ---- prep: out = act?(BN(in)) : cvt(in). bnp: [0:128]=scale [128:256]=shift [256]=alpha ----

__global__ __launch_bounds__(256) void k_prep(const void* __restrict__ in, float* __restrict__ out,
                                              const float* __restrict__ bnp,
                                              const int* __restrict__ dflag) {
    int f = *dflag;
    long i = (long)blockIdx.x * 256 + threadIdx.x;   // grid covers exactly N*DD
    float v;
    if (bnp) {
        int c = (int)(i & 127);
        v = fmaf(((const float*)in)[i], bnp[c], bnp[128 + c]);
        v = (v > 0.f) ? v : bnp[256] * v;
    } else {
        v = ldf(in, i, f);
    }
    out[i] = v;
}

// ---- fp32 GEMM: C[N x 128] = A[N x 128] * W[128 x 128] (+bias, relu) ----
// A (fp32) streamed from global via L1 broadcast (no LDS). W half-tile (64 cols)
// staged once in LDS. 256 thr: 128 rows x 64 cols per block, 8x4 acc/thread.
// LDS pipe load per 4k: 4 waves x 4 ds_read_b128 x 12cyc = 192 < 256 VALU cyc -> VALU-bound.

__global__ __launch_bounds__(256, 4) void k_gemm2(const float* __restrict__ A,
                                                  const void* __restrict__ W, long woff,
                                                  const void* __restrict__ bias,
                                                  float* __restrict__ Cout, int relu,
                                                  const int* __restrict__ dflag) {
    __shared__ float Wl[128][68];    // [k][c], stride 68: b128 reads 2-way conflict (free)
    int f = *dflag;
    int tid = threadIdx.x;
    int rowbase = (blockIdx.x >> 1) * 128;
    int colbase = (blockIdx.x & 1) * 64;

    if (f) {
        const float4* W4 = (const float4*)W + (woff >> 2);
        for (int u = tid; u < 128 * 16; u += 256) {
            int k = u >> 4, cq = u & 15;
            float4 v = W4[k * 32 + (colbase >> 2) + cq];
            *(float4*)&Wl[k][cq * 4] = v;
        }
    } else {
        const __hip_bfloat16* Wb = (const __hip_bfloat16*)W + woff;
        for (int u = tid; u < 128 * 64; u += 256) {
            int k = u >> 6, c = u & 63;
            Wl[k][c] = __bfloat162float(Wb[k * 128 + colbase + c]);
        }
    }
    __syncthreads();

    int tx = tid & 15;               // cols colbase + tx*4 .. +3
    int ty = tid >> 4;               // rows rowbase + ty*8 .. +7
    int r0 = rowbase + ty * 8;
    float acc[8][4];
    #pragma unroll
    for (int i = 0; i < 8; ++i)
        #pragma unroll
        for (int j = 0; j < 4; ++j) acc[i][j] = 0.f;

    const float4* A4 = (const float4*)A;
    bool full = (rowbase + 128) <= N_NODES;

    for (int k4 = 0; k4 < 32; ++k4) {
        float a[8][4];
        if (full) {
            #pragma unroll
            for (int i = 0; i < 8; ++i)
                *(float4*)a[i] = A4[(long)(r0 + i) * 32 + k4];
        } else {
            #pragma unroll
            for (int i = 0; i < 8; ++i) {
                float4 v = make_float4(0.f, 0.f, 0.f, 0.f);
                if (r0 + i < N_NODES) v = A4[(long)(r0 + i) * 32 + k4];
                *(float4*)a[i] = v;
            }
        }
        #pragma unroll
        for (int kk = 0; kk < 4; ++kk) {
            float4 w = *(const float4*)&Wl[k4 * 4 + kk][tx * 4];
            #pragma unroll
            for (int i = 0; i < 8; ++i) {
                acc[i][0] += a[i][kk] * w.x;
                acc[i][1] += a[i][kk] * w.y;
                acc[i][2] += a[i][kk] * w.z;
                acc[i][3] += a[i][kk] * w.w;
            }
        }
    }

    float b4[4] = {0.f, 0.f, 0.f, 0.f};
    if (bias) {
        #pragma unroll
        for (int j = 0; j < 4; ++j) b4[j] = ldf(bias, colbase + tx * 4 + j, f);
    }
    #pragma unroll
    for (int i = 0; i < 8; ++i) {
        int r = r0 + i;
        if (r < N_NODES) {
            float4 o;
            o.x = acc[i][0] + b4[0];
            o.y = acc[i][1] + b4[1];
            o.z = acc[i][2] + b4[2];
            o.w = acc[i][3] + b4[3];
            if (relu) {
                o.x = fmaxf(o.x, 0.f); o.y = fmaxf(o.y, 0.f);
                o.z = fmaxf(o.z, 0.f); o.w = fmaxf(o.w, 0.f);
            }
            *(float4*)&Cout[(long)r * 128 + colbase + tx * 4] = o;
        }
    }
}

// ---- CSR aggregation: out_i = dinv_i*(dinv_i*XW_i + sum_j dinv_j*XW_j) + b ----

__global__ __launch_bounds__(256) void k_agg(const float* __restrict__ XW, const int* __restrict__ rowptr,
                                             const int* __restrict__ adj, const float* __restrict__ dinv,
                                             const void* __restrict__ bias, long boff,
                                             float* __restrict__ outp, const int* __restrict__ dflag) {
    int f = *dflag;
    int wave = threadIdx.x >> 6;
    int lane = threadIdx.x & 63;
    int i = blockIdx.x * 4 + wave;
    if (i >= N_NODES) return;
    const float2* XW2 = (const float2*)XW;
    float di = dinv[i];
    int e0 = rowptr[i], e1 = rowptr[i + 1];
    float2 self = XW2[(size_t)i * 64 + lane];
    float acc0 = di * self.x, acc1 = di * self.y;
    for (int e = e0; e < e1; ++e) {
        int j = adj[e];
        float dj = dinv[j];
        float2 v = XW2[(size_t)j * 64 + lane];
        acc0 += dj * v.x;
        acc1 += dj * v.y;
    }
    float2 r;
    r.x = di * acc0 + ldf(bias, boff + 2 * lane, f);
    r.y = di * acc1 + ldf(bias, boff + 2 * lane + 1, f);
    ((float2*)outp)[(size_t)i * 64 + lane] = r;
}

// ---------------- BatchNorm stats + param prep ----------------

__global__ __launch_bounds__(256) void k_bn_reduce(const float* __restrict__ H, float* __restrict__ sums,
                                                   float* __restrict__ sumsq) {
    int c = threadIdx.x & 127;
    int half = threadIdx.x >> 7;
    float s = 0.f, q = 0.f;
    for (int r = blockIdx.x * 2 + half; r < N_NODES; r += gridDim.x * 2) {
        float v = H[(long)r * 128 + c];
        s += v; q += v * v;
    }
    __shared__ float ls[256], lq[256];
    ls[threadIdx.x] = s; lq[threadIdx.x] = q;
    __syncthreads();
    if (threadIdx.x < 128) {
        atomicAdd(&sums[c], ls[threadIdx.x] + ls[threadIdx.x + 128]);
        atomicAdd(&sumsq[c], lq[threadIdx.x] + lq[threadIdx.x + 128]);
    }
}

// scale[c]=gamma*rsqrt(var+eps); shift[c]=beta-mean*scale; [256]=prelu alpha
__global__ __launch_bounds__(128) void k_bnprep(const float* __restrict__ stats,
                                                const void* __restrict__ g, const void* __restrict__ b,
                                                const void* __restrict__ a, int l,
                                                float* __restrict__ bnp, const int* __restrict__ dflag) {
    int f = *dflag;
    int c = threadIdx.x;
    float mean = stats[c] / (float)N_NODES;
    float var = stats[128 + c] / (float)N_NODES - mean * mean;
    float inv = 1.f / sqrtf(var + BN_EPS);
    float s = ldf(g, (long)l * DD + c, f) * inv;
    bnp[c] = s;
    bnp[128 + c] = ldf(b, (long)l * DD + c, f) - mean * s;
    if (c == 0) bnp[256] = ldf(a, l, f);
}

// emb: BN+PReLU on layer-3 pre-act -> d_out (out dtype) AND fp32 copy for head GEMM
__global__ __launch_bounds__(256) void k_emb(const float* __restrict__ H, const float* __restrict__ bnp,
                                             void* __restrict__ out, float* __restrict__ out32,
                                             const int* __restrict__ dflag) {
    int f = *dflag;
    long idx = (long)blockIdx.x * 256 + threadIdx.x;   // grid covers exactly N*DD
    int c = (int)(idx & 127);
    float al = bnp[256];
    float y = fmaf(H[idx], bnp[c], bnp[128 + c]);
    y = (y > 0.f) ? y : al * y;
    stf(out, idx, y, f);
    out32[idx] = y;
}

// ---- head: logits = hidden @ Wh2 + bh2 ; argmax (first-max tie-break) ----

__global__ __launch_bounds__(256) void k_head(const float* __restrict__ Hd, const void* __restrict__ W2,
                                              const void* __restrict__ b2,
                                              void* __restrict__ out_base,
                                              const int* __restrict__ dflag) {
    __shared__ float Wl[128][40];
    __shared__ float bl[40];
    __shared__ float rv[32][8];
    __shared__ int ri[32][8];
    int f = *dflag;
    int tid = threadIdx.x;
    for (int u = tid; u < 128 * 40; u += 256) Wl[u / 40][u % 40] = ldf(W2, u, f);
    if (tid < 40) bl[tid] = ldf(b2, tid, f);
    __syncthreads();
    int rl = tid >> 3, g = tid & 7;
    long r = (long)blockIdx.x * 32 + rl;            // 3125*32 == N exactly
    float acc[5];
    #pragma unroll
    for (int j = 0; j < 5; ++j) acc[j] = bl[g * 5 + j];
    for (int k = 0; k < 128; ++k) {
        float h = Hd[r * 128 + k];
        #pragma unroll
        for (int j = 0; j < 5; ++j) acc[j] += h * Wl[k][g * 5 + j];
    }
    float best = acc[0]; int bi = 0;
    #pragma unroll
    for (int j = 1; j < 5; ++j)
        if (acc[j] > best) { best = acc[j]; bi = j; }   // strictly > keeps first max
    const long LOG_OFF = (long)N_NODES * DD;
    const long ARG_OFF = (long)N_NODES * (DD + CC);
    #pragma unroll
    for (int j = 0; j < 5; ++j) stf(out_base, LOG_OFF + r * 40 + g * 5 + j, acc[j], f);
    rv[rl][g] = best; ri[rl][g] = g * 5 + bi;
    __syncthreads();
    if (tid < 32) {
        long row = (long)blockIdx.x * 32 + tid;
        float bb = rv[tid][0]; int bbi = ri[tid][0];
        #pragma unroll
        for (int g2 = 1; g2 < 8; ++g2)
            if (rv[tid][g2] > bb) { bb = rv[tid][g2]; bbi = ri[tid][g2]; }
        stf(out_base, ARG_OFF + row, (float)bbi, f);
    }
}

// ---------------- launch ----------------

extern "C" void kernel_launch(void* const* d_in, const int* in_sizes, int n_in,
                              void* d_out, int out_size, void* d_ws, size_t ws_size,
                              hipStream_t stream) {
    const void* x   = d_in[0];
    const int* ei   = (const int*)d_in[1];
    const void* Ws  = d_in[2];
    const void* bs  = d_in[3];
    const void* gam = d_in[4];
    const void* bet = d_in[5];
    const void* pa  = d_in[6];
    const void* Wh1 = d_in[7];
    const void* bh1 = d_in[8];
    const void* Wh2 = d_in[9];
    const void* bh2 = d_in[10];

    char* w = (char*)d_ws;
    int* cnt     = (int*)w;    w += sizeof(int) * N_NODES;
    int* fpos    = (int*)w;    w += sizeof(int) * N_NODES;
    int* rowptr  = (int*)w;    w += sizeof(int) * (N_NODES + 4);
    int* adj     = (int*)w;    w += sizeof(int) * N_EDGES;
    int* bsum    = (int*)w;    w += sizeof(int) * 512;
    int* dflag   = (int*)w;    w += sizeof(int) * 4;
    float* dinv  = (float*)w;  w += sizeof(float) * N_NODES;
    float* stats = (float*)w;  w += sizeof(float) * (6 * DD);
    float* bnp   = (float*)w;  w += sizeof(float) * (3 * 512);
    float* bufA  = (float*)w;  w += sizeof(float) * (size_t)N_NODES * DD;
    float* bufB  = (float*)w;  w += sizeof(float) * (size_t)N_NODES * DD;
    float* bufC  = (float*)w;  w += sizeof(float) * (size_t)N_NODES * DD;

    const int scanBlocks = (N_NODES + 255) / 256;       // 391
    const int edgeBlocks = (N_EDGES + 255) / 256;       // 2344
    const int elemBlocks = (N_NODES * DD) / 256;        // 50000 exact
    const int gemmBlocks = ((N_NODES + 127) / 128) * 2; // 782 row-blocks x 2 col-halves

    k_detect<<<1, 256, 0, stream>>>(x, dflag);
    k_init<<<scanBlocks, 256, 0, stream>>>(cnt, fpos, rowptr, stats);
    k_count<<<edgeBlocks, 256, 0, stream>>>(ei, cnt);
    k_scan1<<<scanBlocks, 256, 0, stream>>>(cnt, rowptr, bsum, dinv);
    k_scan2<<<1, 512, 0, stream>>>(bsum, scanBlocks);
    k_scan3<<<scanBlocks, 256, 0, stream>>>(rowptr, bsum);
    k_fill<<<edgeBlocks, 256, 0, stream>>>(ei, fpos, rowptr, adj);

    for (int l = 0; l < LL; ++l) {
        const void* src = (l == 0) ? x : (const void*)bufA;
        const float* bn = (l == 0) ? nullptr : (bnp + (l - 1) * 512);
        k_prep<<<elemBlocks, 256, 0, stream>>>(src, bufC, bn, dflag);
        k_gemm2<<<gemmBlocks, 256, 0, stream>>>(bufC, Ws, (long)l * DD * DD, nullptr,
                                                bufB, 0, dflag);
        k_agg<<<(N_NODES + 3) / 4, 256, 0, stream>>>(bufB, rowptr, adj, dinv, bs, (long)l * DD,
                                                     bufA, dflag);
        k_bn_reduce<<<256, 256, 0, stream>>>(bufA, stats + l * 2 * DD, stats + l * 2 * DD + DD);
        k_bnprep<<<1, 128, 0, stream>>>(stats + l * 2 * DD, gam, bet, pa, l, bnp + l * 512, dflag);
    }

    k_emb<<<elemBlocks, 256, 0, stream>>>(bufA, bnp + 2 * 512, d_out, bufC, dflag);
    k_gemm2<<<gemmBlocks, 256, 0, stream>>>(bufC, Wh1, 0, bh1, bufB, 1, dflag);
    k_head<<<(N_NODES / 32), 256, 0, stream>>>(bufB, Wh2, bh2, d_out, dflag);
}

// Round 5
// 775.094 us; speedup vs baseline: 2.0269x; 1.3278x over previous
//
#include <hip/hip_runtime.h>
#include <hip/hip_bf16.h>
#include <cstddef>

#define N_NODES 100000
#define N_EDGES 600000
#define DD 128
#define LL 3
#define CC 40
#define BN_EPS 1e-5f

// dtype-adaptive load/store: f32!=0 -> buffer holds float32, else bfloat16.
__device__ __forceinline__ float ldf(const void* p, long i, int f32) {
    return f32 ? ((const float*)p)[i] : __bfloat162float(((const __hip_bfloat16*)p)[i]);
}
__device__ __forceinline__ void stf(void* p, long i, float v, int f32) {
    if (f32) ((float*)p)[i] = v;
    else     ((__hip_bfloat16*)p)[i] = __float2bfloat16(v);
}

// ---------------- dtype detection (fp32 data read as bf16 -> garbage values) ----------------
__global__ __launch_bounds__(256) void k_detect(const void* __restrict__ x, int* __restrict__ dflag) {
    __shared__ int s[256];
    int t = threadIdx.x;
    const __hip_bfloat16* xb = (const __hip_bfloat16*)x;
    int bad = 0;
    for (int i = t; i < 4096; i += 256) {
        float v = __bfloat162float(xb[i]);
        float a = fabsf(v);
        if (!(a < 1e6f)) bad++;
        else if (v != 0.f && a < 1e-30f) bad++;
    }
    s[t] = bad; __syncthreads();
    for (int off = 128; off > 0; off >>= 1) {
        if (t < off) s[t] += s[t + off];
        __syncthreads();
    }
    if (t == 0) *dflag = (s[0] > 64) ? 1 : 0;
}

// ---------------- graph preprocessing ----------------

__global__ __launch_bounds__(256) void k_init(int* cnt, int* fpos, int* rowptr, float* stats) {
    int i = blockIdx.x * 256 + threadIdx.x;
    if (i < N_NODES) { cnt[i] = 0; fpos[i] = 0; }
    if (i < 6 * DD) stats[i] = 0.f;       // 3 layers x (sum[128], sumsq[128])
    if (i == 0) rowptr[N_NODES] = N_EDGES;
}

__global__ __launch_bounds__(256) void k_count(const int* __restrict__ ei, int* __restrict__ cnt) {
    int e = blockIdx.x * 256 + threadIdx.x;
    if (e < N_EDGES) atomicAdd(&cnt[ei[N_EDGES + e]], 1);  // dst row
}

__global__ __launch_bounds__(256) void k_scan1(const int* __restrict__ cnt, int* __restrict__ rowptr,
                                               int* __restrict__ bsum, float* __restrict__ dinv) {
    __shared__ int s[256];
    int t = threadIdx.x;
    int i = blockIdx.x * 256 + t;
    int v = (i < N_NODES) ? cnt[i] : 0;
    if (i < N_NODES) dinv[i] = 1.f / sqrtf((float)(1 + v));  // deg >= 1 (self-loop)
    s[t] = v; __syncthreads();
    for (int off = 1; off < 256; off <<= 1) {
        int x = (t >= off) ? s[t - off] : 0;
        __syncthreads();
        s[t] += x; __syncthreads();
    }
    if (i < N_NODES) rowptr[i] = s[t] - v;
    if (t == 255) bsum[blockIdx.x] = s[255];
}

__global__ __launch_bounds__(512) void k_scan2(int* bsum, int nb) {
    __shared__ int s[512];
    int t = threadIdx.x;
    int v = (t < nb) ? bsum[t] : 0;
    s[t] = v; __syncthreads();
    for (int off = 1; off < 512; off <<= 1) {
        int x = (t >= off) ? s[t - off] : 0;
        __syncthreads();
        s[t] += x; __syncthreads();
    }
    if (t < nb) bsum[t] = s[t] - v;
}

__global__ __launch_bounds__(256) void k_scan3(int* rowptr, const int* __restrict__ bsum) {
    int i = blockIdx.x * 256 + threadIdx.x;
    if (i < N_NODES) rowptr[i] += bsum[blockIdx.x];
}

__global__ __launch_bounds__(256) void k_fill(const int* __restrict__ ei, int* __restrict__ fpos,
                                              const int* __restrict__ rowptr, int* __restrict__ adj) {
    int e = blockIdx.x * 256 + threadIdx.x;
    if (e < N_EDGES) {
        int d = ei[N_EDGES + e];
        int p = atomicAdd(&fpos[d], 1);
        adj[rowptr[d] + p] = ei[e];
    }
}

// ---- row load + optional BN+PReLU. lane holds elements 2*lane, 2*lane+1 ----
__device__ __forceinline__ void load_act(const void* __restrict__ src, long row, int lane, int f,
                                         const float* __restrict__ bnp,
                                         float s0, float s1, float h0, float h1, float al,
                                         float& o0, float& o1) {
    if (bnp) {                      // fp32 pre-activation + BN + PReLU
        float2 v = ((const float2*)src)[row * 64 + lane];
        float y0 = fmaf(v.x, s0, h0), y1 = fmaf(v.y, s1, h1);
        o0 = (y0 > 0.f) ? y0 : al * y0;
        o1 = (y1 > 0.f) ? y1 : al * y1;
    } else if (f) {                 // raw fp32
        float2 v = ((const float2*)src)[row * 64 + lane];
        o0 = v.x; o1 = v.y;
    } else {                        // raw bf16 (2 elems per dword)
        unsigned u = ((const unsigned*)src)[row * 64 + lane];
        o0 = __uint_as_float(u << 16);
        o1 = __uint_as_float(u & 0xffff0000u);
    }
}

// ---- CSR aggregation (agg-first): out_i = dinv_i*(dinv_i*act_i + sum_j dinv_j*act_j) ----
// act = identity for layer 0 (src = x), else BN_{l-1}+PReLU applied inline on pre_{l-1}.

__global__ __launch_bounds__(256) void k_agg(const void* __restrict__ src,
                                             const int* __restrict__ rowptr,
                                             const int* __restrict__ adj,
                                             const float* __restrict__ dinv,
                                             const float* __restrict__ bnp,
                                             float* __restrict__ outp,
                                             const int* __restrict__ dflag) {
    int f = *dflag;
    int lane = threadIdx.x & 63;
    int i = blockIdx.x * 4 + (threadIdx.x >> 6);
    if (i >= N_NODES) return;
    float s0 = 0.f, s1 = 0.f, h0 = 0.f, h1 = 0.f, al = 0.f;
    if (bnp) {
        s0 = bnp[2 * lane];       s1 = bnp[2 * lane + 1];
        h0 = bnp[128 + 2 * lane]; h1 = bnp[129 + 2 * lane];
        al = bnp[256];
    }
    float di = dinv[i];
    int e0 = rowptr[i], e1 = rowptr[i + 1];
    float x0, x1;
    load_act(src, i, lane, f, bnp, s0, s1, h0, h1, al, x0, x1);
    float acc0 = di * x0, acc1 = di * x1;

    for (int base = e0; base < e1; base += 64) {
        int m = e1 - base; if (m > 64) m = 64;
        int aj = (lane < m) ? adj[base + lane] : 0;          // coalesced adjacency load
        float djl = (lane < m) ? dinv[aj] : 0.f;
        int t = 0;
        for (; t + 2 <= m; t += 2) {                          // 2 gathers in flight
            int j0 = __shfl(aj, t), j1 = __shfl(aj, t + 1);
            float d0 = __shfl(djl, t), d1 = __shfl(djl, t + 1);
            float p0, p1, q0, q1;
            load_act(src, j0, lane, f, bnp, s0, s1, h0, h1, al, p0, p1);
            load_act(src, j1, lane, f, bnp, s0, s1, h0, h1, al, q0, q1);
            acc0 += d0 * p0 + d1 * q0;
            acc1 += d0 * p1 + d1 * q1;
        }
        if (t < m) {
            int j0 = __shfl(aj, t);
            float d0 = __shfl(djl, t);
            float p0, p1;
            load_act(src, j0, lane, f, bnp, s0, s1, h0, h1, al, p0, p1);
            acc0 += d0 * p0;
            acc1 += d0 * p1;
        }
    }
    float2 r; r.x = di * acc0; r.y = di * acc1;
    ((float2*)outp)[(size_t)i * 64 + lane] = r;
}

// ---- fp32 GEMM: C[N x 128] = act(A)[N x 128] * W[128 x 128] + bias (opt relu) ----
// A streamed via L1 broadcast; W half-tile (64 cols) in LDS; 8x4 acc/thread.
// bnpA: apply BN+PReLU on A inline (head GEMM). stats: atomicAdd per-col sum/sumsq of C.

__global__ __launch_bounds__(256, 4) void k_gemm2(const float* __restrict__ A,
                                                  const void* __restrict__ W, long woff,
                                                  const void* __restrict__ bias, long boff,
                                                  const float* __restrict__ bnpA,
                                                  float* __restrict__ stats,
                                                  float* __restrict__ Cout, int relu,
                                                  const int* __restrict__ dflag) {
    __shared__ float Wl[128][64];
    __shared__ float sred[16][64];
    int f = *dflag;
    int tid = threadIdx.x;
    int rowbase = (blockIdx.x >> 1) * 128;
    int colbase = (blockIdx.x & 1) * 64;

    if (f) {
        const float4* W4 = (const float4*)W + (woff >> 2);
        for (int u = tid; u < 128 * 16; u += 256) {
            int k = u >> 4, cq = u & 15;
            *(float4*)&Wl[k][cq * 4] = W4[k * 32 + (colbase >> 2) + cq];
        }
    } else {
        const unsigned* Wb = (const unsigned*)((const __hip_bfloat16*)W + woff);
        for (int u = tid; u < 128 * 32; u += 256) {
            int k = u >> 5, c2 = u & 31;
            unsigned v = Wb[k * 64 + (colbase >> 1) + c2];
            Wl[k][c2 * 2]     = __uint_as_float(v << 16);
            Wl[k][c2 * 2 + 1] = __uint_as_float(v & 0xffff0000u);
        }
    }
    __syncthreads();

    int tx = tid & 15;               // cols colbase + tx*4 .. +3
    int ty = tid >> 4;               // rows rowbase + ty*8 .. +7
    int r0 = rowbase + ty * 8;
    float acc[8][4];
    #pragma unroll
    for (int i = 0; i < 8; ++i)
        #pragma unroll
        for (int j = 0; j < 4; ++j) acc[i][j] = 0.f;

    const float4* A4 = (const float4*)A;
    bool full = (rowbase + 128) <= N_NODES;
    float alA = bnpA ? bnpA[256] : 0.f;

    for (int k4 = 0; k4 < 32; ++k4) {
        float a[8][4];
        if (full) {
            #pragma unroll
            for (int i = 0; i < 8; ++i)
                *(float4*)a[i] = A4[(long)(r0 + i) * 32 + k4];
        } else {
            #pragma unroll
            for (int i = 0; i < 8; ++i) {
                float4 v = make_float4(0.f, 0.f, 0.f, 0.f);
                if (r0 + i < N_NODES) v = A4[(long)(r0 + i) * 32 + k4];
                *(float4*)a[i] = v;
            }
        }
        if (bnpA) {
            float4 s4 = ((const float4*)bnpA)[k4];
            float4 h4 = ((const float4*)(bnpA + 128))[k4];
            float sv[4] = {s4.x, s4.y, s4.z, s4.w};
            float hv[4] = {h4.x, h4.y, h4.z, h4.w};
            #pragma unroll
            for (int i = 0; i < 8; ++i)
                #pragma unroll
                for (int kk = 0; kk < 4; ++kk) {
                    float y = fmaf(a[i][kk], sv[kk], hv[kk]);
                    a[i][kk] = (y > 0.f) ? y : alA * y;
                }
        }
        #pragma unroll
        for (int kk = 0; kk < 4; ++kk) {
            float4 w = *(const float4*)&Wl[k4 * 4 + kk][tx * 4];
            #pragma unroll
            for (int i = 0; i < 8; ++i) {
                acc[i][0] += a[i][kk] * w.x;
                acc[i][1] += a[i][kk] * w.y;
                acc[i][2] += a[i][kk] * w.z;
                acc[i][3] += a[i][kk] * w.w;
            }
        }
    }

    float b4[4] = {0.f, 0.f, 0.f, 0.f};
    if (bias) {
        #pragma unroll
        for (int j = 0; j < 4; ++j) b4[j] = ldf(bias, boff + colbase + tx * 4 + j, f);
    }
    float ls[4] = {0.f, 0.f, 0.f, 0.f};
    float lq[4] = {0.f, 0.f, 0.f, 0.f};
    #pragma unroll
    for (int i = 0; i < 8; ++i) {
        int r = r0 + i;
        if (r < N_NODES) {
            float o[4];
            #pragma unroll
            for (int j = 0; j < 4; ++j) {
                float v = acc[i][j] + b4[j];
                if (relu) v = fmaxf(v, 0.f);
                o[j] = v;
                ls[j] += v;
                lq[j] += v * v;
            }
            *(float4*)&Cout[(long)r * 128 + colbase + tx * 4] = make_float4(o[0], o[1], o[2], o[3]);
        }
    }
    if (stats) {
        #pragma unroll
        for (int j = 0; j < 4; ++j) sred[ty][tx * 4 + j] = ls[j];
        __syncthreads();
        if (tid < 64) {
            float t = 0.f;
            #pragma unroll
            for (int g = 0; g < 16; ++g) t += sred[g][tid];
            atomicAdd(&stats[colbase + tid], t);
        }
        __syncthreads();
        #pragma unroll
        for (int j = 0; j < 4; ++j) sred[ty][tx * 4 + j] = lq[j];
        __syncthreads();
        if (tid < 64) {
            float t = 0.f;
            #pragma unroll
            for (int g = 0; g < 16; ++g) t += sred[g][tid];
            atomicAdd(&stats[128 + colbase + tid], t);
        }
    }
}

// scale[c]=gamma*rsqrt(var+eps); shift[c]=beta-mean*scale; [256]=prelu alpha
__global__ __launch_bounds__(128) void k_bnprep(const float* __restrict__ stats,
                                                const void* __restrict__ g, const void* __restrict__ b,
                                                const void* __restrict__ a, int l,
                                                float* __restrict__ bnp, const int* __restrict__ dflag) {
    int f = *dflag;
    int c = threadIdx.x;
    float mean = stats[c] / (float)N_NODES;
    float var = stats[128 + c] / (float)N_NODES - mean * mean;
    float inv = 1.f / sqrtf(var + BN_EPS);
    float s = ldf(g, (long)l * DD + c, f) * inv;
    bnp[c] = s;
    bnp[128 + c] = ldf(b, (long)l * DD + c, f) - mean * s;
    if (c == 0) bnp[256] = ldf(a, l, f);
}

// emb: BN_2+PReLU on pre_3 -> d_out (out dtype)
__global__ __launch_bounds__(256) void k_emb(const float* __restrict__ H, const float* __restrict__ bnp,
                                             void* __restrict__ out, const int* __restrict__ dflag) {
    int f = *dflag;
    long idx = (long)blockIdx.x * 256 + threadIdx.x;   // grid covers exactly N*DD
    int c = (int)(idx & 127);
    float al = bnp[256];
    float y = fmaf(H[idx], bnp[c], bnp[128 + c]);
    y = (y > 0.f) ? y : al * y;
    stf(out, idx, y, f);
}

// ---- head: logits = hidden @ Wh2 + bh2 ; argmax (first-max tie-break) ----

__global__ __launch_bounds__(256) void k_head(const float* __restrict__ Hd, const void* __restrict__ W2,
                                              const void* __restrict__ b2,
                                              void* __restrict__ out_base,
                                              const int* __restrict__ dflag) {
    __shared__ float Wl[128][40];
    __shared__ float bl[40];
    __shared__ float rv[32][8];
    __shared__ int ri[32][8];
    int f = *dflag;
    int tid = threadIdx.x;
    for (int u = tid; u < 128 * 40; u += 256) Wl[u / 40][u % 40] = ldf(W2, u, f);
    if (tid < 40) bl[tid] = ldf(b2, tid, f);
    __syncthreads();
    int rl = tid >> 3, g = tid & 7;
    long r = (long)blockIdx.x * 32 + rl;            // 3125*32 == N exactly
    float acc[5];
    #pragma unroll
    for (int j = 0; j < 5; ++j) acc[j] = bl[g * 5 + j];
    for (int k = 0; k < 128; ++k) {
        float h = Hd[r * 128 + k];
        #pragma unroll
        for (int j = 0; j < 5; ++j) acc[j] += h * Wl[k][g * 5 + j];
    }
    float best = acc[0]; int bi = 0;
    #pragma unroll
    for (int j = 1; j < 5; ++j)
        if (acc[j] > best) { best = acc[j]; bi = j; }   // strictly > keeps first max
    const long LOG_OFF = (long)N_NODES * DD;
    const long ARG_OFF = (long)N_NODES * (DD + CC);
    #pragma unroll
    for (int j = 0; j < 5; ++j) stf(out_base, LOG_OFF + r * 40 + g * 5 + j, acc[j], f);
    rv[rl][g] = best; ri[rl][g] = g * 5 + bi;
    __syncthreads();
    if (tid < 32) {
        long row = (long)blockIdx.x * 32 + tid;
        float bb = rv[tid][0]; int bbi = ri[tid][0];
        #pragma unroll
        for (int g2 = 1; g2 < 8; ++g2)
            if (rv[tid][g2] > bb) { bb = rv[tid][g2]; bbi = ri[tid][g2]; }
        stf(out_base, ARG_OFF + row, (float)bbi, f);
    }
}

// ---------------- launch ----------------

extern "C" void kernel_launch(void* const* d_in, const int* in_sizes, int n_in,
                              void* d_out, int out_size, void* d_ws, size_t ws_size,
                              hipStream_t stream) {
    const void* x   = d_in[0];
    const int* ei   = (const int*)d_in[1];
    const void* Ws  = d_in[2];
    const void* bs  = d_in[3];
    const void* gam = d_in[4];
    const void* bet = d_in[5];
    const void* pa  = d_in[6];
    const void* Wh1 = d_in[7];
    const void* bh1 = d_in[8];
    const void* Wh2 = d_in[9];
    const void* bh2 = d_in[10];

    char* w = (char*)d_ws;
    int* cnt     = (int*)w;    w += sizeof(int) * N_NODES;
    int* fpos    = (int*)w;    w += sizeof(int) * N_NODES;
    int* rowptr  = (int*)w;    w += sizeof(int) * (N_NODES + 4);
    int* adj     = (int*)w;    w += sizeof(int) * N_EDGES;
    int* bsum    = (int*)w;    w += sizeof(int) * 512;
    int* dflag   = (int*)w;    w += sizeof(int) * 4;
    float* dinv  = (float*)w;  w += sizeof(float) * N_NODES;
    float* stats = (float*)w;  w += sizeof(float) * (6 * DD);
    float* bnp   = (float*)w;  w += sizeof(float) * (3 * 512);
    float* bufA  = (float*)w;  w += sizeof(float) * (size_t)N_NODES * DD;
    float* bufB  = (float*)w;  w += sizeof(float) * (size_t)N_NODES * DD;

    const int scanBlocks = (N_NODES + 255) / 256;       // 391
    const int edgeBlocks = (N_EDGES + 255) / 256;       // 2344
    const int elemBlocks = (N_NODES * DD) / 256;        // 50000 exact
    const int gemmBlocks = ((N_NODES + 127) / 128) * 2; // 782 row-blocks x 2 col-halves
    const int aggBlocks  = (N_NODES + 3) / 4;           // 25000

    k_detect<<<1, 256, 0, stream>>>(x, dflag);
    k_init<<<scanBlocks, 256, 0, stream>>>(cnt, fpos, rowptr, stats);
    k_count<<<edgeBlocks, 256, 0, stream>>>(ei, cnt);
    k_scan1<<<scanBlocks, 256, 0, stream>>>(cnt, rowptr, bsum, dinv);
    k_scan2<<<1, 512, 0, stream>>>(bsum, scanBlocks);
    k_scan3<<<scanBlocks, 256, 0, stream>>>(rowptr, bsum);
    k_fill<<<edgeBlocks, 256, 0, stream>>>(ei, fpos, rowptr, adj);

    for (int l = 0; l < LL; ++l) {
        const void* src = (l == 0) ? x : (const void*)bufB;
        const float* bn = (l == 0) ? nullptr : (bnp + (l - 1) * 512);
        k_agg<<<aggBlocks, 256, 0, stream>>>(src, rowptr, adj, dinv, bn, bufA, dflag);
        k_gemm2<<<gemmBlocks, 256, 0, stream>>>(bufA, Ws, (long)l * DD * DD, bs, (long)l * DD,
                                                nullptr, stats + l * 256, bufB, 0, dflag);
        k_bnprep<<<1, 128, 0, stream>>>(stats + l * 256, gam, bet, pa, l, bnp + l * 512, dflag);
    }

    k_emb<<<elemBlocks, 256, 0, stream>>>(bufB, bnp + 2 * 512, d_out, dflag);
    k_gemm2<<<gemmBlocks, 256, 0, stream>>>(bufB, Wh1, 0, bh1, 0, bnp + 2 * 512,
                                            nullptr, bufA, 1, dflag);
    k_head<<<(N_NODES / 32), 256, 0, stream>>>(bufA, Wh2, bh2, d_out, dflag);
}